// Round 5
// baseline (249.983 us; speedup 1.0000x reference)
//
#include <hip/hip_runtime.h>

// SegmentationAugmentation: fused affine-grid + trilinear grid_sample (border,
// align_corners=False) for input (float out) and label (bool-as-float out).
//
// R4: R3 was mixed LDS-pipe (~53% of per-CU cycles: 16 ds_read_b32/thread,
// LDS unit shared per-CU) + VALU (~110 inst/thread) bound. Two changes:
//  (a) pair z-reads as unaligned 8B LDS loads -> ds_read2_b32 (16 -> 8 insts)
//  (b) per-(o2,o3) row params (r-bases, wx/wy weights) precomputed by a tiny
//      pre-kernel into d_ws; main kernel loads them uniformly (SGPRs),
//      removing ~35 VALU inst/thread of block-uniform x/y math.
//
// Transform structure (T[2]=T[6]=T[8]=T[9]=+-0, offsets nonzero): x/y sample
// coords depend only on (o2,o3); z coord only on o4. Dropping the exact-zero
// terms is bit-identical (the +-0 add is always followed by adding nonzero).
//
// CORRECTNESS-CRITICAL: label output is a hard comparator (acc > 0.5) with
// voxels ~0.5 ulp from the boundary; all float math must stay bit-exact vs
// numpy: contract(off), strict reference op order, w = (wz*wy)*wx, reference
// corner accumulation order. The pre-kernel computes the x/y path with the
// EXACT same expressions as before (same bits); staging/reads only move data.

#define NV 128
#define TOTAL (8 * NV * NV * NV)

// ---- pre-kernel: per-(o2,o3) row parameters -> d_ws ----
// rp[2*i]   = {r00,r01,r10,r11} as int-bits (row base element offsets)
// rp[2*i+1] = {wx0,wx1,wy0,wy1}
__global__ __launch_bounds__(128) void rowparam_kernel(
    const float* __restrict__ T, float4* __restrict__ rp)
{
#pragma clang fp contract(off)
    const int idx = blockIdx.x * 128 + threadIdx.x;   // o2*128 + o3
    const int o3 = idx & (NV - 1);
    const int o2 = idx >> 7;

    float p2 = (2.0f * (float)o2 + 1.0f) / 128.0f - 1.0f;
    float p3 = (2.0f * (float)o3 + 1.0f) / 128.0f - 1.0f;
    float ux = (T[0] * p2 + T[1] * p3) + T[3];
    float uy = (T[4] * p2 + T[5] * p3) + T[7];
    float gx = ((ux + 1.0f) * 128.0f - 1.0f) * 0.5f;
    float gy = ((uy + 1.0f) * 128.0f - 1.0f) * 0.5f;
    gx = fminf(fmaxf(gx, 0.0f), 127.0f);
    gy = fminf(fmaxf(gy, 0.0f), 127.0f);
    float fx0f = floorf(gx), fy0f = floorf(gy);
    float fx = gx - fx0f;
    float fy = gy - fy0f;
    int ix0 = (int)fx0f, iy0 = (int)fy0f;
    int ix1 = min(ix0 + 1, NV - 1);
    int iy1 = min(iy0 + 1, NV - 1);

    float4 ri, rw;
    ri.x = __int_as_float((ix0 * NV + iy0) * NV);
    ri.y = __int_as_float((ix0 * NV + iy1) * NV);
    ri.z = __int_as_float((ix1 * NV + iy0) * NV);
    ri.w = __int_as_float((ix1 * NV + iy1) * NV);
    rw.x = 1.0f - fx;  rw.y = fx;
    rw.z = 1.0f - fy;  rw.w = fy;
    rp[2 * idx] = ri;
    rp[2 * idx + 1] = rw;
}

__global__ __launch_bounds__(128) void seg_aug_kernel(
    const float* __restrict__ in,
    const float* __restrict__ lab,
    const float* __restrict__ T,   // 16 floats; only row 2 used here
    const float4* __restrict__ rp,
    float* __restrict__ out_in,
    float* __restrict__ out_lab)
{
#pragma clang fp contract(off)
    __shared__ float s[8 * NV];              // rows: in{00,01,10,11}, lab{00,01,10,11}

    const int t = threadIdx.x;               // 0..127 = o4 (innermost output dim)
    const int row = blockIdx.x & 16383;      // (o2,o3)
    const int b = blockIdx.x >> 14;

    // ---- uniform row params (scalar loads) ----
    const float4 ri = rp[2 * row];
    const float4 rw = rp[2 * row + 1];
    const int r00 = __builtin_amdgcn_readfirstlane(__float_as_int(ri.x));
    const int r01 = __builtin_amdgcn_readfirstlane(__float_as_int(ri.y));
    const int r10 = __builtin_amdgcn_readfirstlane(__float_as_int(ri.z));
    const int r11 = __builtin_amdgcn_readfirstlane(__float_as_int(ri.w));
    const float wx0 = rw.x, wx1 = rw.y, wy0 = rw.z, wy1 = rw.w;

    // ---- stage 8 rows into LDS (4 KB) via lds-DMA ----
    const size_t bbase = (size_t)b << 21;    // b * 128^3
    const float* ibp = in  + bbase;
    const float* lbp = lab + bbase;
    {
        const int rid = t >> 5;              // 0..3 selects row {00,01,10,11}
        const int seg = t & 31;              // float4 index within the row
        int rb = (rid & 2) ? ((rid & 1) ? r11 : r10)
                           : ((rid & 1) ? r01 : r00);
        const int off = rb + seg * 4;
        __builtin_amdgcn_global_load_lds(ibp + off, &s[t * 4],       16, 0, 0);
        __builtin_amdgcn_global_load_lds(lbp + off, &s[512 + t * 4], 16, 0, 0);
    }

    // ---- per-thread z path (overlaps with staging latency) ----
    float p4 = (2.0f * (float)t + 1.0f) / 128.0f - 1.0f;
    float uz = T[10] * p4 + T[11];
    float gz = ((uz + 1.0f) * 128.0f - 1.0f) * 0.5f;
    gz = fminf(fmaxf(gz, 0.0f), 127.0f);
    float fz0f = floorf(gz);
    float fz = gz - fz0f;
    int iz0 = (int)fz0f;
    float wz0 = 1.0f - fz, wz1 = fz;

    // pair-read base: zb=min(iz0,126); pair=(s[zb],s[zb+1]).
    //   z0-plane value = (iz0==127) ? pair.y : pair.x
    //   z1-plane value = pair.y  (covers the min(iz0+1,127) clamp)
    const int zb = min(iz0, NV - 2);
    const bool hi = (iz0 == NV - 1);

    __syncthreads();

    // unaligned 8B LDS loads -> ds_read2_b32 (values bit-identical)
    #define PAIR(ROW, A, B)                                       \
        float A, B;                                               \
        {                                                         \
            float2 _p;                                            \
            __builtin_memcpy(&_p, &s[(ROW) * NV + zb], 8);        \
            A = _p.x; B = _p.y;                                   \
        }

    PAIR(0, ia00, ib00)   // in,  (x0,y0)
    PAIR(1, ia01, ib01)   // in,  (x0,y1)
    PAIR(2, ia10, ib10)   // in,  (x1,y0)
    PAIR(3, ia11, ib11)   // in,  (x1,y1)
    PAIR(4, la00, lb00)   // lab, (x0,y0)
    PAIR(5, la01, lb01)
    PAIR(6, la10, lb10)
    PAIR(7, la11, lb11)
    #undef PAIR

    // z0-plane values (select for the clamped edge), z1-plane = pair.y
    float vi000 = hi ? ib00 : ia00;
    float vi010 = hi ? ib01 : ia01;
    float vi100 = hi ? ib10 : ia10;
    float vi110 = hi ? ib11 : ia11;
    float vl000 = hi ? lb00 : la00;
    float vl010 = hi ? lb01 : la01;
    float vl100 = hi ? lb10 : la10;
    float vl110 = hi ? lb11 : la11;

    // weights, reference order: w = (wz*wy)*wx
    float tz0y0 = wz0 * wy0, tz0y1 = wz0 * wy1;
    float tz1y0 = wz1 * wy0, tz1y1 = wz1 * wy1;
    float w1 = tz0y0 * wx0, w2 = tz0y0 * wx1;
    float w3 = tz0y1 * wx0, w4 = tz0y1 * wx1;
    float w5 = tz1y0 * wx0, w6 = tz1y0 * wx1;
    float w7 = tz1y1 * wx0, w8 = tz1y1 * wx1;

    // reference accumulation order: z outer, y mid, x inner
    float acc_i = 0.0f;
    acc_i = acc_i + vi000 * w1;
    acc_i = acc_i + vi100 * w2;
    acc_i = acc_i + vi010 * w3;
    acc_i = acc_i + vi110 * w4;
    acc_i = acc_i + ib00 * w5;
    acc_i = acc_i + ib10 * w6;
    acc_i = acc_i + ib01 * w7;
    acc_i = acc_i + ib11 * w8;

    float acc_l = 0.0f;
    acc_l = acc_l + vl000 * w1;
    acc_l = acc_l + vl100 * w2;
    acc_l = acc_l + vl010 * w3;
    acc_l = acc_l + vl110 * w4;
    acc_l = acc_l + lb00 * w5;
    acc_l = acc_l + lb10 * w6;
    acc_l = acc_l + lb01 * w7;
    acc_l = acc_l + lb11 * w8;

    const int oidx = blockIdx.x * NV + t;    // (b,o2,o3,o4) flat
    out_in[oidx]  = acc_i;
    out_lab[oidx] = (acc_l > 0.5f) ? 1.0f : 0.0f;
}

extern "C" void kernel_launch(void* const* d_in, const int* in_sizes, int n_in,
                              void* d_out, int out_size, void* d_ws, size_t ws_size,
                              hipStream_t stream) {
    const float* in  = (const float*)d_in[0];
    const float* lab = (const float*)d_in[1];
    const float* T   = (const float*)d_in[2];
    float* out_in  = (float*)d_out;
    float* out_lab = (float*)d_out + TOTAL;
    float4* rp = (float4*)d_ws;              // 16384 * 32 B = 512 KB << ws

    rowparam_kernel<<<128, 128, 0, stream>>>(T, rp);
    seg_aug_kernel<<<TOTAL / 128, 128, 0, stream>>>(in, lab, T, rp,
                                                    out_in, out_lab);
}